// Round 10
// baseline (4220.263 us; speedup 1.0000x reference)
//
#include <hip/hip_runtime.h>
#include <cstddef>

#define NMAT 512
#define MRHS 12
#define NBLK 64
#define NTHR 256

__device__ __forceinline__ float rdlane(float v, int l) {
    return __int_as_float(__builtin_amdgcn_readlane(__float_as_int(v), l));
}

// ---------------- device-scope grid barrier (64 blocks, all co-resident) ----------------
__device__ __forceinline__ void gridbar(unsigned* cnt, unsigned* gen) {
    __syncthreads();
    if (threadIdx.x == 0) {
        __threadfence();
        unsigned g = __hip_atomic_load(gen, __ATOMIC_RELAXED, __HIP_MEMORY_SCOPE_AGENT);
        unsigned a = __hip_atomic_fetch_add(cnt, 1u, __ATOMIC_ACQ_REL, __HIP_MEMORY_SCOPE_AGENT);
        if (a == NBLK - 1) {
            __hip_atomic_store(cnt, 0u, __ATOMIC_RELAXED, __HIP_MEMORY_SCOPE_AGENT);
            __hip_atomic_fetch_add(gen, 1u, __ATOMIC_RELEASE, __HIP_MEMORY_SCOPE_AGENT);
        } else {
            while (__hip_atomic_load(gen, __ATOMIC_ACQUIRE, __HIP_MEMORY_SCOPE_AGENT) == g)
                __builtin_amdgcn_s_sleep(2);
        }
        __threadfence();
    }
    __syncthreads();
}

// ---------------- Stage 1: A = LU = constant_part + sum_e r[e] * M[e]; resets barrier -------
__global__ void __launch_bounds__(256) k_setup(const float* __restrict__ M,
                                               const float* __restrict__ r,
                                               const float* __restrict__ cpart,
                                               float* __restrict__ A,
                                               float* __restrict__ LU,
                                               unsigned* __restrict__ bar) {
    if (blockIdx.x == 0 && threadIdx.x == 0) { bar[0] = 0u; bar[1] = 0u; }
    __shared__ float rs[1024];
    const int tid = threadIdx.x;
    for (int i = tid; i < 1024; i += 256) rs[i] = r[i];
    __syncthreads();
    const int idx2 = blockIdx.x * 256 + tid;          // 0..131071
    const float2* __restrict__ M2 = (const float2*)M;
    float2 a = ((const float2*)cpart)[idx2];
    float ax = a.x, ay = a.y;
#pragma unroll 16
    for (int e = 0; e < 1024; ++e) {
        float2 v = M2[(size_t)e * 131072u + idx2];
        float rv = rs[e];
        ax += rv * v.x; ay += rv * v.y;
    }
    float2 o; o.x = ax; o.y = ay;
    ((float2*)A)[idx2] = o;
    ((float2*)LU)[idx2] = o;
}

// ================= mega kernel device functions (256 thr = 4 waves) =================

// LU panel p: diag 64x64 rank-1 (row i on wave (i&3) slot (i>>2)) + L21 rows by
// left-looking substitution (lane = row, readlane broadcasts, rows staged via LDS
// so global reads stay coalesced). Writes transposed packed panel into LUT rows
// [k0,k1) cols [k0, k0+NR) and dinv.
__device__ __forceinline__ void panel_f(const float* __restrict__ LU,
                                        float* __restrict__ LUT,
                                        float* __restrict__ dinvG, int p,
                                        int w, int lane, int tid,
                                        float (*piv)[64], float* U11lds, float* dinvLDS,
                                        float* stage) {
    const int k0 = p * 64, k1 = k0 + 64;
    const int NG = 7 - p;
    float dreg[16];
#pragma unroll
    for (int s = 0; s < 16; ++s)
        dreg[s] = LU[(size_t)(k0 + s * 4 + w) * NMAT + k0 + lane];
    for (int j = 0; j < 64; ++j) {
        if (w == (j & 3)) {
#pragma unroll
            for (int s = 0; s < 16; ++s)
                if ((j >> 2) == s) {
                    piv[j & 1][lane] = dreg[s];
                    U11lds[j * 65 + lane] = dreg[s];
                }
        }
        __syncthreads();
        float pvl = piv[j & 1][lane];
        float pj = __shfl(pvl, j);
        float pinv = 1.0f / pj;
        if (tid == 0) dinvLDS[j] = pinv;
#pragma unroll
        for (int s = 0; s < 16; ++s) {
            int i = s * 4 + w;
            if (i > j) {                         // wave-uniform
                float rv = dreg[s];
                float l = __shfl(rv, j) * pinv;
                float upd = rv - l * pvl;
                rv = (lane > j) ? upd : rv;
                rv = (lane == j) ? l : rv;
                dreg[s] = rv;
            }
        }
    }
    __syncthreads();
    if (w == 0) dinvG[k0 + lane] = dinvLDS[lane];
    // transposed packed diag -> LUT rows k0..k1
#pragma unroll
    for (int q = 0; q < 16; ++q) {
        int c = w * 16 + q;
        LUT[(size_t)(k0 + c) * NMAT + k0 + lane] = U11lds[lane * 65 + c];
    }
    // L21 row groups (64 rows each): stage via LDS (coalesced), substitute, write LUT
    for (int g = 0; g < NG; ++g) {
        __syncthreads();
        for (int idx = tid; idx < 4096; idx += NTHR) {
            int row = idx >> 6, col = idx & 63;
            stage[row * 65 + col] = LU[(size_t)(k1 + g * 64 + row) * NMAT + k0 + col];
        }
        __syncthreads();
        // each wave handles 16 of the 64 rows? No: all 4 waves cooperate, lane = row,
        // wave w handles row block — keep lane=row across one wave only (w==g%... )
        // simplest: wave (g&3) does this group -> but we want parallelism across waves.
        // Instead: each wave takes rows [w*16, w*16+16)? Substitution needs full row in
        // one lane. Assign: wave w, lane = row index within its quarter? That breaks
        // readlane layout. Keep: all waves process same group cooperatively by
        // splitting the 64 rows: lane = row, wave w handles columns? No — do per-wave
        // rows: wave w owns rows where (row&3)==w is wrong for readlane too.
        // Simplest correct: every wave processes 64 rows redundantly is wasteful;
        // instead wave w processes group rows with lane=row only when w == (g & 3)?
        // NG<=7, 4 waves: process groups round-robin with full-wave rows.
        if (w == (g & 3)) {
            float colreg[64];
#pragma unroll
            for (int c = 0; c < 64; ++c) colreg[c] = stage[lane * 65 + c];
#pragma unroll
            for (int j = 0; j < 64; ++j) {
                float lj = colreg[j] * dinvLDS[j];
                colreg[j] = lj;
                float rowv = U11lds[j * 65 + lane];   // U11 row j (per-lane element)
#pragma unroll
                for (int jj = j + 1; jj < 64; ++jj)
                    colreg[jj] -= lj * rdlane(rowv, jj);
            }
#pragma unroll
            for (int c = 0; c < 64; ++c)
                LUT[(size_t)(k0 + c) * NMAT + k1 + g * 64 + lane] = colreg[c];
        }
    }
    __syncthreads();
}

// update tile: redundant register trsm (stable substitution) + role work.
// role 0: write Y^T into LUT (U12). role>=1: A22 row-tile -= L21 @ Y.
__device__ __forceinline__ void tile_f(float* __restrict__ LU,
                                       float* __restrict__ LUT,
                                       int p, int ct, int role,
                                       int w, int lane, int tid,
                                       float* yLDS) {
    const int k0 = p * 64, k1 = k0 + 64;
    const int jc0 = k1 + ct * 64;
    float y[64];
#pragma unroll
    for (int i = 0; i < 64; ++i)
        y[i] = LU[(size_t)(k0 + i) * NMAT + jc0 + lane];
#pragma unroll
    for (int tc = 0; tc < 4; ++tc) {
        float cv[16];
#pragma unroll
        for (int q = 0; q < 16; ++q)
            cv[q] = LUT[(size_t)(k0 + tc * 16 + q) * NMAT + k0 + lane];
#pragma unroll
        for (int q = 0; q < 16; ++q) {
            const int t = tc * 16 + q;
            float yt = y[t];
#pragma unroll
            for (int i = t + 1; i < 64; ++i)
                y[i] -= rdlane(cv[q], i) * yt;
        }
    }
    if (role == 0) {
        if (w == 0) {
#pragma unroll
            for (int i = 0; i < 64; ++i) yLDS[i * 65 + lane] = y[i];
        }
        __syncthreads();
        for (int idx = tid; idx < 4096; idx += NTHR) {
            int jc = idx >> 6, i = idx & 63;
            LUT[(size_t)(jc0 + jc) * NMAT + k0 + i] = yLDS[i * 65 + jc];
        }
        __syncthreads();
        return;
    }
    const int r0 = k1 + (role - 1) * 64;
    float acc[16];
#pragma unroll
    for (int rr = 0; rr < 16; ++rr)
        acc[rr] = LU[(size_t)(r0 + w * 16 + rr) * NMAT + jc0 + lane];
#pragma unroll
    for (int kc = 0; kc < 8; ++kc) {
        float Lc[8];
#pragma unroll
        for (int q = 0; q < 8; ++q)
            Lc[q] = LUT[(size_t)(k0 + kc * 8 + q) * NMAT + r0 + lane];
#pragma unroll
        for (int q = 0; q < 8; ++q) {
            float yk = y[kc * 8 + q];
#pragma unroll
            for (int rr = 0; rr < 16; ++rr)
                acc[rr] -= rdlane(Lc[q], w * 16 + rr) * yk;
        }
    }
#pragma unroll
    for (int rr = 0; rr < 16; ++rr)
        LU[(size_t)(r0 + w * 16 + rr) * NMAT + jc0 + lane] = acc[rr];
}

__device__ __forceinline__ void solve_f(const float* __restrict__ LUT,
                                        const float* __restrict__ dinv,
                                        const float* __restrict__ B,
                                        float* __restrict__ W, int c, int lane, int mode) {
    float y[8];
    if (mode) {
#pragma unroll
        for (int s = 0; s < 8; ++s) y[s] = B[(s * 64 + lane) * MRHS + c];
#pragma unroll
        for (int js = 0; js < 8; ++js) {
#pragma unroll 4
            for (int jl = 0; jl < 64; ++jl) {
                const int j = js * 64 + jl;
                const float* __restrict__ col = &LUT[(size_t)j * NMAT];
                float yj = __shfl(y[js], jl);
                if (lane > jl) y[js] -= col[js * 64 + lane] * yj;
#pragma unroll
                for (int s = js + 1; s < 8; ++s) y[s] -= col[s * 64 + lane] * yj;
            }
        }
    } else {
#pragma unroll
        for (int s = 0; s < 8; ++s) y[s] = 0.f;
        y[7] = (lane == 52 + c) ? 1.0f : 0.0f;
        for (int jl = 52; jl < 63; ++jl) {
            const float* __restrict__ col = &LUT[(size_t)(448 + jl) * NMAT];
            float yj = __shfl(y[7], jl);
            if (lane > jl) y[7] -= col[448 + lane] * yj;
        }
    }
#pragma unroll
    for (int js = 7; js >= 0; --js) {
#pragma unroll 4
        for (int jl = 63; jl >= 0; --jl) {
            const int j = js * 64 + jl;
            const float* __restrict__ col = &LUT[(size_t)j * NMAT];
            float xj = __shfl(y[js], jl) * dinv[j];
            float t = y[js] - col[js * 64 + lane] * xj;
            y[js] = (lane < jl) ? t : ((lane == jl) ? xj : y[js]);
#pragma unroll
            for (int s = 0; s < js; ++s) y[s] -= col[s * 64 + lane] * xj;
        }
    }
#pragma unroll
    for (int s = 0; s < 8; ++s) {
        int row = s * 64 + lane;
        if (mode) W[row * MRHS + c] += y[s];
        else      W[row * MRHS + c] = y[s];
    }
}

__device__ __forceinline__ void resid_f(const float* __restrict__ A,
                                        const float* __restrict__ W,
                                        float* __restrict__ R, int row, int lane) {
    double acc[MRHS];
#pragma unroll
    for (int cc = 0; cc < MRHS; ++cc) acc[cc] = 0.0;
    for (int k = lane; k < NMAT; k += 64) {
        float a = A[(size_t)row * NMAT + k];
#pragma unroll
        for (int cc = 0; cc < MRHS; ++cc) acc[cc] += (double)a * (double)W[k * MRHS + cc];
    }
#pragma unroll
    for (int cc = 0; cc < MRHS; ++cc) {
        double v = acc[cc];
#pragma unroll
        for (int off = 32; off > 0; off >>= 1) v += __shfl_xor(v, off);
        if (lane == cc) R[row * MRHS + cc] = (float)(((row == 500 + cc) ? 1.0 : 0.0) - v);
    }
}

// ---------------- the mega kernel: LU + solves + refinement + out ----------------
__global__ void __launch_bounds__(NTHR, 1) k_mega(float* __restrict__ LU,
                                                  float* __restrict__ LUT,
                                                  const float* __restrict__ A,
                                                  float* __restrict__ W, float* __restrict__ R,
                                                  float* __restrict__ dinvG,
                                                  const float* __restrict__ x,
                                                  float* __restrict__ out,
                                                  unsigned* __restrict__ bar) {
    __shared__ float piv[2][64];
    __shared__ float U11lds[64 * 65];
    __shared__ float dinvLDS[64];
    __shared__ float yLDS[64 * 65];
    __shared__ float stage[64 * 65];
    const int bid = blockIdx.x, tid = threadIdx.x;
    const int w = tid >> 6, lane = tid & 63;
    unsigned* cnt = bar; unsigned* gen = bar + 1;

    if (bid == 0) panel_f(LU, LUT, dinvG, 0, w, lane, tid, piv, U11lds, dinvLDS, stage);
    gridbar(cnt, gen);
    for (int p = 0; p < 7; ++p) {
        const int nrt = 7 - p;                      // trailing row/col tiles
        // phase A: column tile 0 (all roles) -> feeds panel p+1
        if (bid <= nrt) tile_f(LU, LUT, p, 0, bid, w, lane, tid, yLDS);
        gridbar(cnt, gen);
        // phase B: block 0 factors panel p+1; others do remaining column tiles
        if (bid == 0) {
            panel_f(LU, LUT, dinvG, p + 1, w, lane, tid, piv, U11lds, dinvLDS, stage);
        } else {
            const int ntasks = (nrt - 1) * (nrt + 1);
            for (int t = bid - 1; t < ntasks; t += NBLK - 1)
                tile_f(LU, LUT, p, 1 + t / (nrt + 1), t % (nrt + 1), w, lane, tid, yLDS);
        }
        gridbar(cnt, gen);
    }
    // solves + 2 iterative-refinement steps
    if (bid < MRHS && tid < 64) solve_f(LUT, dinvG, R, W, bid, lane, 0);
    gridbar(cnt, gen);
    for (int it = 0; it < 2; ++it) {
#pragma unroll
        for (int rr = 0; rr < 2; ++rr)
            resid_f(A, W, R, (bid * 4 + w) * 2 + rr, lane);
        gridbar(cnt, gen);
        if (bid < MRHS && tid < 64) solve_f(LUT, dinvG, R, W, bid, lane, 1);
        gridbar(cnt, gen);
    }
    // out = W @ e  (x viewed as (12, 4096))
    const float4* __restrict__ x4 = (const float4*)x;
    for (int idx = bid * NTHR + tid; idx < 512 * 1024; idx += NBLK * NTHR) {
        int i = idx >> 10, p4 = idx & 1023;
        float ax = 0.f, ay = 0.f, az = 0.f, aw = 0.f;
#pragma unroll
        for (int k = 0; k < MRHS; ++k) {
            float wv = W[i * MRHS + k];
            float4 v = x4[k * 1024 + p4];
            ax += wv * v.x; ay += wv * v.y; az += wv * v.z; aw += wv * v.w;
        }
        float4 o; o.x = ax; o.y = ay; o.z = az; o.w = aw;
        ((float4*)out)[idx] = o;
    }
}

extern "C" void kernel_launch(void* const* d_in, const int* in_sizes, int n_in,
                              void* d_out, int out_size, void* d_ws, size_t ws_size,
                              hipStream_t stream) {
    (void)in_sizes; (void)n_in; (void)out_size; (void)ws_size;
    const float* M     = (const float*)d_in[0];
    const float* r     = (const float*)d_in[1];
    const float* cpart = (const float*)d_in[2];
    const float* x     = (const float*)d_in[3];
    float* out = (float*)d_out;
    float* ws  = (float*)d_ws;

    float* LU   = ws;                 // 262144
    float* A    = ws + 262144;        // 262144
    float* LUT  = ws + 524288;        // 262144
    float* W    = ws + 786432;        // 6144
    float* R    = ws + 792576;        // 6144
    float* dinv = ws + 798720;        // 512
    unsigned* bar = (unsigned*)(ws + 799232);

    k_setup<<<dim3(512), 256, 0, stream>>>(M, r, cpart, A, LU, bar);
    k_mega<<<dim3(NBLK), NTHR, 0, stream>>>(LU, LUT, A, W, R, dinv, x, out, bar);
}

// Round 11
// 1965.534 us; speedup vs baseline: 2.1471x; 2.1471x over previous
//
#include <hip/hip_runtime.h>
#include <cstddef>

#define NMAT 512
#define MRHS 12

__device__ __forceinline__ float rdlane(float v, int l) {
    return __int_as_float(__builtin_amdgcn_readlane(__float_as_int(v), l));
}

// ---------------- Stage 1: A = LU = constant_part + sum_e r[e] * M[e] ----------------
// 512 blocks x 256 thr; each thread owns one float2 (512*512 = 131072 float2).
__global__ void __launch_bounds__(256) k_setup(const float* __restrict__ M,
                                               const float* __restrict__ r,
                                               const float* __restrict__ cpart,
                                               float* __restrict__ A,
                                               float* __restrict__ LU) {
    __shared__ float rs[1024];
    const int tid = threadIdx.x;
    for (int i = tid; i < 1024; i += 256) rs[i] = r[i];
    __syncthreads();
    const int idx2 = blockIdx.x * 256 + tid;          // 0..131071
    const float2* __restrict__ M2 = (const float2*)M;
    float2 a = ((const float2*)cpart)[idx2];
    float ax = a.x, ay = a.y;
#pragma unroll 16
    for (int e = 0; e < 1024; ++e) {
        float2 v = M2[(size_t)e * 131072u + idx2];
        float rv = rs[e];
        ax += rv * v.x; ay += rv * v.y;
    }
    float2 o; o.x = ax; o.y = ay;
    ((float2*)A)[idx2] = o;
    ((float2*)LU)[idx2] = o;
}

// ---------------- LU panel (no pivoting), NB=64, 512 thr = 8 waves (proven R8) ----------
// Diag 64x64: row i on wave (i&7) slot (i>>3), lane = column; rank-1 with pivot-row LDS
// broadcast. L21 rows: lane = row, left-looking substitution, U11 via LDS + readlane.
// Outputs: LUT rows [k0,k0+64) cols [k0,k0+NR) = transposed packed panel; dinvG.
template <int NR>
__global__ void __launch_bounds__(512) k_panel(const float* __restrict__ LU,
                                               float* __restrict__ LUT,
                                               float* __restrict__ dinvG,
                                               int k0) {
    constexpr int NG = (NR - 64) / 64;   // L21 row-groups
    __shared__ float piv[2][64];
    __shared__ float U11lds[64 * 65];
    __shared__ float dinvLDS[64];
    const int tid = threadIdx.x;
    const int w = tid >> 6, lane = tid & 63;
    const int k1 = k0 + 64;

    // early-issue L21 rows (independent of diag factor; latency hidden under it)
    float colreg[64];
    if (NG > 0 && w < NG) {
#pragma unroll
        for (int c = 0; c < 64; ++c)
            colreg[c] = LU[(size_t)(k1 + w * 64 + lane) * NMAT + k0 + c];
    }
    // diag rows
    float dreg[8];
#pragma unroll
    for (int s = 0; s < 8; ++s)
        dreg[s] = LU[(size_t)(k0 + s * 8 + w) * NMAT + k0 + lane];

    for (int j = 0; j < 64; ++j) {
        if (w == (j & 7)) {
#pragma unroll
            for (int s = 0; s < 8; ++s)
                if ((j >> 3) == s) {
                    piv[j & 1][lane] = dreg[s];
                    U11lds[j * 65 + lane] = dreg[s];
                }
        }
        __syncthreads();
        float pvl = piv[j & 1][lane];
        float pj = __shfl(pvl, j);
        float pinv = 1.0f / pj;
        if (tid == 0) dinvLDS[j] = pinv;
#pragma unroll
        for (int s = 0; s < 8; ++s) {
            int i = s * 8 + w;
            if (i > j) {                        // wave-uniform
                float rv = dreg[s];
                float l = __shfl(rv, j) * pinv;
                float upd = rv - l * pvl;
                rv = (lane > j) ? upd : rv;
                rv = (lane == j) ? l : rv;
                dreg[s] = rv;
            }
        }
    }
    __syncthreads();
    if (w == 0) dinvG[k0 + lane] = dinvLDS[lane];
    // transposed diag -> LUT rows k0..k1 (LDS stride-65 read, coalesced write)
#pragma unroll
    for (int q = 0; q < 8; ++q) {
        int c = w * 8 + q;
        LUT[(size_t)(k0 + c) * NMAT + k0 + lane] = U11lds[lane * 65 + c];
    }
    // L21 sweep: l_r U11 = a_r, forward substitution per lane-row
    if (NG > 0 && w < NG) {
#pragma unroll
        for (int j = 0; j < 64; ++j) {
            float lj = colreg[j] * dinvLDS[j];
            colreg[j] = lj;
            float rowv = U11lds[j * 65 + lane];   // row j of packed diag, per-lane
#pragma unroll
            for (int jj = j + 1; jj < 64; ++jj)
                colreg[jj] -= lj * rdlane(rowv, jj);
        }
#pragma unroll
        for (int c = 0; c < 64; ++c)
            LUT[(size_t)(k0 + c) * NMAT + k1 + w * 64 + lane] = colreg[c];
    }
}

// ---------------- fused trsm + trailing update (proven R8) ----------------
__global__ void __launch_bounds__(256) k_update(float* __restrict__ LU,
                                                float* __restrict__ LUT,
                                                int k0) {
    __shared__ float yLDS[64 * 65];
    const int k1 = k0 + 64;
    const int jc0 = k1 + blockIdx.x * 64;
    const int tid = threadIdx.x;
    const int w = tid >> 6, lane = tid & 63;

    float y[64];
#pragma unroll
    for (int i = 0; i < 64; ++i)
        y[i] = LU[(size_t)(k0 + i) * NMAT + jc0 + lane];
#pragma unroll
    for (int tc = 0; tc < 4; ++tc) {
        float cv[16];
#pragma unroll
        for (int q = 0; q < 16; ++q)
            cv[q] = LUT[(size_t)(k0 + tc * 16 + q) * NMAT + k0 + lane];
#pragma unroll
        for (int q = 0; q < 16; ++q) {
            const int t = tc * 16 + q;
            float yt = y[t];
#pragma unroll
            for (int i = t + 1; i < 64; ++i)
                y[i] -= rdlane(cv[q], i) * yt;
        }
    }

    if (blockIdx.y == 0) {
        if (w == 0) {
#pragma unroll
            for (int i = 0; i < 64; ++i) yLDS[i * 65 + lane] = y[i];
        }
        __syncthreads();
        for (int idx = tid; idx < 4096; idx += 256) {
            int jc = idx >> 6, i = idx & 63;
            LUT[(size_t)(jc0 + jc) * NMAT + k0 + i] = yLDS[i * 65 + jc];
        }
        return;
    }
    const int r0 = k1 + (blockIdx.y - 1) * 64;
    float acc[16];
#pragma unroll
    for (int rr = 0; rr < 16; ++rr)
        acc[rr] = LU[(size_t)(r0 + w * 16 + rr) * NMAT + jc0 + lane];
#pragma unroll
    for (int kc = 0; kc < 8; ++kc) {
        float Lc[8];
#pragma unroll
        for (int q = 0; q < 8; ++q)
            Lc[q] = LUT[(size_t)(k0 + kc * 8 + q) * NMAT + r0 + lane];  // L21 col, coalesced
#pragma unroll
        for (int q = 0; q < 8; ++q) {
            float yk = y[kc * 8 + q];
#pragma unroll
            for (int rr = 0; rr < 16; ++rr)
                acc[rr] -= rdlane(Lc[q], w * 16 + rr) * yk;
        }
    }
#pragma unroll
    for (int rr = 0; rr < 16; ++rr)
        LU[(size_t)(r0 + w * 16 + rr) * NMAT + jc0 + lane] = acc[rr];
}

// ---------------- BLOCKED triangular solves, 12 RHS, 1 wave per RHS ----------------
// Off-diagonal corrections = parallel coalesced loads + readlane FMA (off the chain).
// Diagonal 64-chain runs on PRE-LOADED registers (Lc/Uc) at shfl latency.
// Diag block (ds): Dc[q] = LU[base+lane][base+q] = LUT[(base+q)*512 + base+lane].
// mode 0: b = e_{500+c} (forward collapses to last diag block). mode 1: b = B[:,c], W += x.
__global__ void __launch_bounds__(64) k_solve(const float* __restrict__ LUT,
                                              const float* __restrict__ dinv,
                                              const float* __restrict__ B,
                                              float* __restrict__ W, int mode) {
    const int c = blockIdx.x;
    const int lane = threadIdx.x;
    float y[8];
    float Dc[64];
    if (mode) {
#pragma unroll
        for (int s = 0; s < 8; ++s) y[s] = B[(s * 64 + lane) * MRHS + c];
        // blocked forward: L (unit diag)
#pragma unroll
        for (int js = 0; js < 8; ++js) {
            const int base = js * 64;
            // corrections: y[js] -= sum_{s<js} L_{js,s} y_s   (parallel loads)
            float a0 = 0.f, a1 = 0.f;
            for (int s = 0; s < js; ++s) {
#pragma unroll 8
                for (int m = 0; m < 64; m += 2) {
                    a0 += LUT[(size_t)(s * 64 + m)     * NMAT + base + lane] * rdlane(y[s], m);
                    a1 += LUT[(size_t)(s * 64 + m + 1) * NMAT + base + lane] * rdlane(y[s], m + 1);
                }
            }
            y[js] -= (a0 + a1);
            // preload diag block column-regs, then register-latency chain
#pragma unroll
            for (int q = 0; q < 64; ++q)
                Dc[q] = LUT[(size_t)(base + q) * NMAT + base + lane];
#pragma unroll 4
            for (int jl = 0; jl < 63; ++jl) {
                float yj = __shfl(y[js], jl);
                if (lane > jl) y[js] -= Dc[jl] * yj;
            }
        }
    } else {
#pragma unroll
        for (int s = 0; s < 8; ++s) y[s] = 0.f;
        y[7] = (lane == 52 + c) ? 1.0f : 0.0f;
        // forward collapses to last diag block, entries >= 52
#pragma unroll
        for (int q = 0; q < 64; ++q)
            Dc[q] = LUT[(size_t)(448 + q) * NMAT + 448 + lane];
#pragma unroll 4
        for (int jl = 52; jl < 63; ++jl) {
            float yj = __shfl(y[7], jl);
            if (lane > jl) y[7] -= Dc[jl] * yj;
        }
    }
    // blocked backward: U x = y
    const float dv = dinv[/*will index per block*/ lane];  // placeholder overwritten below
    (void)dv;
#pragma unroll
    for (int js = 7; js >= 0; --js) {
        const int base = js * 64;
        // corrections: y[js] -= sum_{s>js} U_{js,s} x_s   (parallel loads)
        float a0 = 0.f, a1 = 0.f;
        for (int s = js + 1; s < 8; ++s) {
#pragma unroll 8
            for (int m = 0; m < 64; m += 2) {
                a0 += LUT[(size_t)(s * 64 + m)     * NMAT + base + lane] * rdlane(y[s], m);
                a1 += LUT[(size_t)(s * 64 + m + 1) * NMAT + base + lane] * rdlane(y[s], m + 1);
            }
        }
        y[js] -= (a0 + a1);
        // preload diag block + dinv, then register-latency chain
#pragma unroll
        for (int q = 0; q < 64; ++q)
            Dc[q] = LUT[(size_t)(base + q) * NMAT + base + lane];
        float dvb = dinv[base + lane];
#pragma unroll 4
        for (int jl = 63; jl >= 0; --jl) {
            float xj = __shfl(y[js], jl) * rdlane(dvb, jl);
            float t = y[js] - Dc[jl] * xj;
            y[js] = (lane < jl) ? t : ((lane == jl) ? xj : y[js]);
        }
    }
#pragma unroll
    for (int s = 0; s < 8; ++s) {
        int row = s * 64 + lane;
        if (mode) W[row * MRHS + c] += y[s];
        else      W[row * MRHS + c] = y[s];
    }
}

// ---------------- residual R = I[:,500:512] - A @ W  (f64 accumulate) ----------------
__global__ void __launch_bounds__(64) k_resid(const float* __restrict__ A,
                                              const float* __restrict__ W,
                                              float* __restrict__ R) {
    const int row = blockIdx.x;
    const int lane = threadIdx.x;
    double acc[MRHS];
#pragma unroll
    for (int cc = 0; cc < MRHS; ++cc) acc[cc] = 0.0;
    for (int k = lane; k < NMAT; k += 64) {
        float a = A[(size_t)row * NMAT + k];
#pragma unroll
        for (int cc = 0; cc < MRHS; ++cc) acc[cc] += (double)a * (double)W[k * MRHS + cc];
    }
#pragma unroll
    for (int cc = 0; cc < MRHS; ++cc) {
        double v = acc[cc];
#pragma unroll
        for (int off = 32; off > 0; off >>= 1) v += __shfl_xor(v, off);
        if (lane == cc) R[row * MRHS + cc] = (float)(((row == 500 + cc) ? 1.0 : 0.0) - v);
    }
}

// ---------------- out[i][p] = sum_k W[i][k] * e[k][p] ----------------
__global__ void __launch_bounds__(256) k_out(const float* __restrict__ W,
                                             const float* __restrict__ x,
                                             float* __restrict__ out) {
    const int p4 = blockIdx.x * 256 + threadIdx.x;  // 0..1023
    const int i = blockIdx.y;
    const float4* __restrict__ x4 = (const float4*)x;
    float ax = 0.f, ay = 0.f, az = 0.f, aw = 0.f;
#pragma unroll
    for (int k = 0; k < MRHS; ++k) {
        float w = W[i * MRHS + k];
        float4 v = x4[k * 1024 + p4];
        ax += w * v.x; ay += w * v.y; az += w * v.z; aw += w * v.w;
    }
    float4 o; o.x = ax; o.y = ay; o.z = az; o.w = aw;
    ((float4*)out)[(size_t)i * 1024 + p4] = o;
}

extern "C" void kernel_launch(void* const* d_in, const int* in_sizes, int n_in,
                              void* d_out, int out_size, void* d_ws, size_t ws_size,
                              hipStream_t stream) {
    (void)in_sizes; (void)n_in; (void)out_size; (void)ws_size;
    const float* M     = (const float*)d_in[0];
    const float* r     = (const float*)d_in[1];
    const float* cpart = (const float*)d_in[2];
    const float* x     = (const float*)d_in[3];
    float* out = (float*)d_out;
    float* ws  = (float*)d_ws;

    float* LU   = ws;                 // 262144
    float* A    = ws + 262144;        // 262144
    float* LUT  = ws + 524288;        // 262144
    float* W    = ws + 786432;        // 6144
    float* R    = ws + 792576;        // 6144
    float* dinv = ws + 798720;        // 512

    // Stage 1: A = LU = constant_part + sum_e r[e] M[e]
    k_setup<<<dim3(512), 256, 0, stream>>>(M, r, cpart, A, LU);

    // Stage 2: blocked LU (no pivoting), NB = 64; factored parts live in LUT only.
    for (int p = 0; p < 8; ++p) {
        const int k0 = p * 64;
        switch (p) {
            case 0: k_panel<512><<<1, 512, 0, stream>>>(LU, LUT, dinv, k0); break;
            case 1: k_panel<448><<<1, 512, 0, stream>>>(LU, LUT, dinv, k0); break;
            case 2: k_panel<384><<<1, 512, 0, stream>>>(LU, LUT, dinv, k0); break;
            case 3: k_panel<320><<<1, 512, 0, stream>>>(LU, LUT, dinv, k0); break;
            case 4: k_panel<256><<<1, 512, 0, stream>>>(LU, LUT, dinv, k0); break;
            case 5: k_panel<192><<<1, 512, 0, stream>>>(LU, LUT, dinv, k0); break;
            case 6: k_panel<128><<<1, 512, 0, stream>>>(LU, LUT, dinv, k0); break;
            case 7: k_panel< 64><<<1, 512, 0, stream>>>(LU, LUT, dinv, k0); break;
        }
        const int nc = NMAT - k0 - 64;
        if (nc > 0)
            k_update<<<dim3(nc / 64, nc / 64 + 1), 256, 0, stream>>>(LU, LUT, k0);
    }

    // Stage 3: W = A^{-1} I[:,500:512], + 2 iterative-refinement steps
    k_solve<<<dim3(MRHS), 64, 0, stream>>>(LUT, dinv, R /*unused*/, W, 0);
    for (int it = 0; it < 2; ++it) {
        k_resid<<<dim3(NMAT), 64, 0, stream>>>(A, W, R);
        k_solve<<<dim3(MRHS), 64, 0, stream>>>(LUT, dinv, R, W, 1);
    }

    // Stage 4: out = W @ e
    k_out<<<dim3(4, 512), 256, 0, stream>>>(W, x, out);
}